// Round 4
// baseline (462.021 us; speedup 1.0000x reference)
//
#include <hip/hip_runtime.h>
#include <math.h>

#define DIM 3072
#define SEQ 8192
#define NROWS (3 * DIM)      // 9216 GEMV output rows
#define NBLK 1024            // 4 blocks/CU x 256 CUs -- co-resident (launch_bounds(256,4))
#define NWAVE (NBLK * 4)     // 4096 waves; SEQ/NWAVE = 2 LN rows per wave

__device__ __forceinline__ float silu_f(float v) {
    return v / (1.0f + __expf(-v));
}

// Fused: GEMV (silu(emb) @ W.T + b) -> release counter -> LayerNorm+affine.
// LN row-A x-loads are issued BEFORE the acquire-spin so HBM stays saturated
// across the GEMV->LN transition.
__global__ __launch_bounds__(256, 4) void fused_adaln_kernel(
    const float* __restrict__ x, const float* __restrict__ emb,
    const float* __restrict__ W, const float* __restrict__ b,
    float* __restrict__ out, float* __restrict__ gate,
    float* __restrict__ shift, float* __restrict__ scale,
    unsigned int* counter)
{
    __shared__ float s[DIM];
    const int t = threadIdx.x;
    const int wid = t >> 6;
    const int lane = t & 63;
    const int wgid = blockIdx.x * 4 + wid;     // global wave id, 0..NWAVE-1

    // stage silu(emb) into LDS (once per block, single barrier)
    {
        const float4* emb4 = (const float4*)emb;
        float4* sw4 = (float4*)s;
        #pragma unroll
        for (int k = 0; k < 3; ++k) {
            int i = t + k * 256;               // float4 index < 768
            float4 v = emb4[i];
            v.x = silu_f(v.x); v.y = silu_f(v.y);
            v.z = silu_f(v.z); v.w = silu_f(v.w);
            sw4[i] = v;
        }
    }
    __syncthreads();
    const float4* s4 = (const float4*)s;

    // ---- GEMV phase: one W row per wave, grid-stride ----
    for (int row = wgid; row < NROWS; row += NWAVE) {
        const float4* w4 = (const float4*)(W + (size_t)row * DIM);
        float acc = 0.f;
        #pragma unroll
        for (int k = 0; k < 12; ++k) {
            float4 w = w4[lane + 64 * k];
            float4 v = s4[lane + 64 * k];
            acc += w.x * v.x + w.y * v.y + w.z * v.z + w.w * v.w;
        }
        #pragma unroll
        for (int off = 32; off > 0; off >>= 1)
            acc += __shfl_xor(acc, off, 64);
        if (lane == 0) {
            float e = acc + b[row];
            int i = row / 3;
            int r = row - 3 * i;
            if (r == 0)      shift[i] = e;
            else if (r == 1) scale[i] = e;
            else             gate[i]  = e;
        }
    }

    // ---- publish: make this block's shift/scale/gate visible device-wide ----
    __threadfence();
    __syncthreads();
    if (t == 0)
        __hip_atomic_fetch_add(counter, 1u, __ATOMIC_RELEASE,
                               __HIP_MEMORY_SCOPE_AGENT);

    const float4* sc4 = (const float4*)scale;
    const float4* sh4 = (const float4*)shift;

    // ---- LN row A (wgid): stats first, THEN wait, then apply ----
    {
        const int row = wgid;                              // 0..4095
        const float4* x4 = (const float4*)(x + (size_t)row * DIM);
        float4* o4 = (float4*)(out + (size_t)row * DIM);
        float4 v[12];
        float sum = 0.f, sq = 0.f;
        #pragma unroll
        for (int k = 0; k < 12; ++k) {
            v[k] = x4[lane + 64 * k];
            sum += v[k].x + v[k].y + v[k].z + v[k].w;
            sq  += v[k].x * v[k].x + v[k].y * v[k].y + v[k].z * v[k].z + v[k].w * v[k].w;
        }
        #pragma unroll
        for (int off = 32; off > 0; off >>= 1) {
            sum += __shfl_xor(sum, off, 64);
            sq  += __shfl_xor(sq,  off, 64);
        }
        const float mean = sum * (1.0f / DIM);
        const float rstd = rsqrtf(sq * (1.0f / DIM) - mean * mean + 1e-6f);

        // GEMV globally done? (x-read latency already spent above)
        while (__hip_atomic_load(counter, __ATOMIC_ACQUIRE,
                                 __HIP_MEMORY_SCOPE_AGENT) < (unsigned)NBLK)
            __builtin_amdgcn_s_sleep(8);

        #pragma unroll
        for (int k = 0; k < 12; ++k) {
            int i = lane + 64 * k;
            float4 sc = sc4[i];
            float4 sh = sh4[i];
            float4 r;
            r.x = (v[k].x - mean) * rstd * sc.x + sh.x;
            r.y = (v[k].y - mean) * rstd * sc.y + sh.y;
            r.z = (v[k].z - mean) * rstd * sc.z + sh.z;
            r.w = (v[k].w - mean) * rstd * sc.w + sh.w;
            o4[i] = r;
        }
    }

    // ---- LN row B (wgid + NWAVE): counter already satisfied ----
    {
        const int row = wgid + NWAVE;                      // 4096..8191
        const float4* x4 = (const float4*)(x + (size_t)row * DIM);
        float4* o4 = (float4*)(out + (size_t)row * DIM);
        float4 v[12];
        float sum = 0.f, sq = 0.f;
        #pragma unroll
        for (int k = 0; k < 12; ++k) {
            v[k] = x4[lane + 64 * k];
            sum += v[k].x + v[k].y + v[k].z + v[k].w;
            sq  += v[k].x * v[k].x + v[k].y * v[k].y + v[k].z * v[k].z + v[k].w * v[k].w;
        }
        #pragma unroll
        for (int off = 32; off > 0; off >>= 1) {
            sum += __shfl_xor(sum, off, 64);
            sq  += __shfl_xor(sq,  off, 64);
        }
        const float mean = sum * (1.0f / DIM);
        const float rstd = rsqrtf(sq * (1.0f / DIM) - mean * mean + 1e-6f);

        #pragma unroll
        for (int k = 0; k < 12; ++k) {
            int i = lane + 64 * k;
            float4 sc = sc4[i];
            float4 sh = sh4[i];
            float4 r;
            r.x = (v[k].x - mean) * rstd * sc.x + sh.x;
            r.y = (v[k].y - mean) * rstd * sc.y + sh.y;
            r.z = (v[k].z - mean) * rstd * sc.z + sh.z;
            r.w = (v[k].w - mean) * rstd * sc.w + sh.w;
            o4[i] = r;
        }
    }
}

extern "C" void kernel_launch(void* const* d_in, const int* in_sizes, int n_in,
                              void* d_out, int out_size, void* d_ws, size_t ws_size,
                              hipStream_t stream) {
    const float* x   = (const float*)d_in[0];  // [1, 8192, 3072]
    const float* emb = (const float*)d_in[1];  // [1, 3072]
    const float* W   = (const float*)d_in[2];  // [9216, 3072]
    const float* b   = (const float*)d_in[3];  // [9216]
    float* out   = (float*)d_out;                      // [1,8192,3072] flat
    float* gate  = out + (size_t)SEQ * DIM;            // [1,3072] appended
    float* shift = (float*)d_ws;                       // [3072]
    float* scale = shift + DIM;                        // [3072]
    unsigned int* counter = (unsigned int*)(scale + DIM);

    hipMemsetAsync(counter, 0, sizeof(unsigned int), stream);
    fused_adaln_kernel<<<NBLK, 256, 0, stream>>>(x, emb, W, b, out, gate,
                                                 shift, scale, counter);
}

// Round 6
// 200.149 us; speedup vs baseline: 2.3084x; 2.3084x over previous
//
#include <hip/hip_runtime.h>
#include <math.h>

#define DIM 3072
#define SEQ 8192
#define NROWS (3 * DIM)      // 9216 GEMV output rows
#define NBLK 1024            // 4 blocks/CU x 256 CUs, co-resident (launch_bounds(256,4))
#define NWAVE (NBLK * 4)     // 4096 waves; SEQ/NWAVE = 2 LN rows per wave

__device__ __forceinline__ float silu_f(float v) {
    return v / (1.0f + __expf(-v));
}

// Fused: GEMV (silu(emb) @ W.T + b) -> counter sync -> LayerNorm+affine.
// Sync design (round-4 lesson): writer = release atomicAdd (flushes L2 to MALL);
// reader = RELAXED poll on lane 0 only (no cache invalidate per iteration),
// then ONE acquire fence per wave after the poll succeeds.
__global__ __launch_bounds__(256, 4) void fused_adaln_kernel(
    const float* __restrict__ x, const float* __restrict__ emb,
    const float* __restrict__ W, const float* __restrict__ b,
    float* __restrict__ out, float* __restrict__ gate,
    float* __restrict__ shift, float* __restrict__ scale,
    unsigned int* __restrict__ counter)
{
    __shared__ float s[DIM];
    const int t = threadIdx.x;
    const int wid = t >> 6;
    const int lane = t & 63;
    const int wgid = blockIdx.x * 4 + wid;     // global wave id, 0..NWAVE-1

    // stage silu(emb) into LDS (once per block, single barrier)
    {
        const float4* emb4 = (const float4*)emb;
        float4* sw4 = (float4*)s;
        #pragma unroll
        for (int k = 0; k < 3; ++k) {
            int i = t + k * 256;               // float4 index < 768
            float4 v = emb4[i];
            v.x = silu_f(v.x); v.y = silu_f(v.y);
            v.z = silu_f(v.z); v.w = silu_f(v.w);
            sw4[i] = v;
        }
    }
    __syncthreads();
    const float4* s4 = (const float4*)s;

    // ---- GEMV phase: one W row per wave, grid-stride ----
    for (int row = wgid; row < NROWS; row += NWAVE) {
        const float4* w4 = (const float4*)(W + (size_t)row * DIM);
        float acc = 0.f;
        #pragma unroll
        for (int k = 0; k < 12; ++k) {
            float4 w = w4[lane + 64 * k];
            float4 v = s4[lane + 64 * k];
            acc += w.x * v.x + w.y * v.y + w.z * v.z + w.w * v.w;
        }
        #pragma unroll
        for (int off = 32; off > 0; off >>= 1)
            acc += __shfl_xor(acc, off, 64);
        if (lane == 0) {
            float e = acc + b[row];
            int i = row / 3;
            int r = row - 3 * i;
            if (r == 0)      shift[i] = e;
            else if (r == 1) scale[i] = e;
            else             gate[i]  = e;
        }
    }

    // ---- publish this block's GEMV results (release -> flush to MALL) ----
    __syncthreads();
    if (t == 0)
        __hip_atomic_fetch_add(counter, 1u, __ATOMIC_RELEASE,
                               __HIP_MEMORY_SCOPE_AGENT);

    // ---- LN row A: load + stats BEFORE the wait (hides GEMV tail + sync) ----
    const int rowA = wgid;                                 // 0..4095
    const float4* xA = (const float4*)(x + (size_t)rowA * DIM);
    float4 v[12];
    float meanA, rstdA;
    {
        float sum = 0.f, sq = 0.f;
        #pragma unroll
        for (int k = 0; k < 12; ++k) {
            v[k] = xA[lane + 64 * k];
            sum += v[k].x + v[k].y + v[k].z + v[k].w;
            sq  += v[k].x * v[k].x + v[k].y * v[k].y + v[k].z * v[k].z + v[k].w * v[k].w;
        }
        #pragma unroll
        for (int off = 32; off > 0; off >>= 1) {
            sum += __shfl_xor(sum, off, 64);
            sq  += __shfl_xor(sq,  off, 64);
        }
        meanA = sum * (1.0f / DIM);
        rstdA = rsqrtf(sq * (1.0f / DIM) - meanA * meanA + 1e-6f);
    }

    // ---- wait: relaxed poll (no invalidates), then ONE acquire fence ----
    if (t == 0) {
        while (__hip_atomic_load(counter, __ATOMIC_RELAXED,
                                 __HIP_MEMORY_SCOPE_AGENT) < (unsigned)NBLK)
            __builtin_amdgcn_s_sleep(8);
    }
    __syncthreads();
    __builtin_amdgcn_fence(__ATOMIC_ACQUIRE, "agent");

    const float4* sc4 = (const float4*)scale;
    const float4* sh4 = (const float4*)shift;

    // ---- apply row A ----
    {
        float4* o4 = (float4*)(out + (size_t)rowA * DIM);
        #pragma unroll
        for (int k = 0; k < 12; ++k) {
            int i = lane + 64 * k;
            float4 sc = sc4[i];
            float4 sh = sh4[i];
            float4 r;
            r.x = (v[k].x - meanA) * rstdA * sc.x + sh.x;
            r.y = (v[k].y - meanA) * rstdA * sc.y + sh.y;
            r.z = (v[k].z - meanA) * rstdA * sc.z + sh.z;
            r.w = (v[k].w - meanA) * rstdA * sc.w + sh.w;
            o4[i] = r;
        }
    }

    // ---- LN row B (wgid + NWAVE): straight through ----
    {
        const int row = wgid + NWAVE;                      // 4096..8191
        const float4* x4 = (const float4*)(x + (size_t)row * DIM);
        float4* o4 = (float4*)(out + (size_t)row * DIM);
        float4 u[12];
        float sum = 0.f, sq = 0.f;
        #pragma unroll
        for (int k = 0; k < 12; ++k) {
            u[k] = x4[lane + 64 * k];
            sum += u[k].x + u[k].y + u[k].z + u[k].w;
            sq  += u[k].x * u[k].x + u[k].y * u[k].y + u[k].z * u[k].z + u[k].w * u[k].w;
        }
        #pragma unroll
        for (int off = 32; off > 0; off >>= 1) {
            sum += __shfl_xor(sum, off, 64);
            sq  += __shfl_xor(sq,  off, 64);
        }
        const float mean = sum * (1.0f / DIM);
        const float rstd = rsqrtf(sq * (1.0f / DIM) - mean * mean + 1e-6f);

        #pragma unroll
        for (int k = 0; k < 12; ++k) {
            int i = lane + 64 * k;
            float4 sc = sc4[i];
            float4 sh = sh4[i];
            float4 r;
            r.x = (u[k].x - mean) * rstd * sc.x + sh.x;
            r.y = (u[k].y - mean) * rstd * sc.y + sh.y;
            r.z = (u[k].z - mean) * rstd * sc.z + sh.z;
            r.w = (u[k].w - mean) * rstd * sc.w + sh.w;
            o4[i] = r;
        }
    }
}

extern "C" void kernel_launch(void* const* d_in, const int* in_sizes, int n_in,
                              void* d_out, int out_size, void* d_ws, size_t ws_size,
                              hipStream_t stream) {
    const float* x   = (const float*)d_in[0];  // [1, 8192, 3072]
    const float* emb = (const float*)d_in[1];  // [1, 3072]
    const float* W   = (const float*)d_in[2];  // [9216, 3072]
    const float* b   = (const float*)d_in[3];  // [9216]
    float* out   = (float*)d_out;                      // [1,8192,3072] flat
    float* gate  = out + (size_t)SEQ * DIM;            // [1,3072] appended
    float* shift = (float*)d_ws;                       // [3072]
    float* scale = shift + DIM;                        // [3072]
    unsigned int* counter = (unsigned int*)(scale + DIM);

    hipMemsetAsync(counter, 0, sizeof(unsigned int), stream);
    fused_adaln_kernel<<<NBLK, 256, 0, stream>>>(x, emb, W, b, out, gate,
                                                 shift, scale, counter);
}

// Round 7
// 68.087 us; speedup vs baseline: 6.7858x; 2.9396x over previous
//
#include <hip/hip_runtime.h>
#include <math.h>

#define DIM 3072
#define SEQ 8192
#define NROWS (3 * DIM)   // 9216 GEMV output rows

__device__ __forceinline__ float silu_f(float v) {
    return v / (1.0f + __expf(-v));
}

// One W row per wave (4 rows per 256-thread block). silu(emb) staged in LDS
// once per block (single barrier); wave-local shuffle reduction only.
// (round-3 proven version, unchanged)
__global__ __launch_bounds__(256, 4) void gemv3_kernel(
    const float* __restrict__ emb, const float* __restrict__ W,
    const float* __restrict__ b, float* __restrict__ shift,
    float* __restrict__ scale, float* __restrict__ gate)
{
    __shared__ float s[DIM];
    const int t = threadIdx.x;
    const float4* emb4 = (const float4*)emb;
    float4* s4 = (float4*)s;

    #pragma unroll
    for (int k = 0; k < 3; ++k) {
        int i = t + k * 256;                 // float4 index < 768
        float4 v = emb4[i];
        v.x = silu_f(v.x); v.y = silu_f(v.y);
        v.z = silu_f(v.z); v.w = silu_f(v.w);
        s4[i] = v;
    }
    __syncthreads();

    const int wid = t >> 6;
    const int lane = t & 63;
    const int row = blockIdx.x * 4 + wid;    // 0..NROWS-1, grid = NROWS/4
    const float4* w4 = (const float4*)(W + (size_t)row * DIM);

    float acc = 0.f;
    #pragma unroll
    for (int k = 0; k < 12; ++k) {
        float4 w = w4[lane + 64 * k];
        float4 v = s4[lane + 64 * k];
        acc += w.x * v.x + w.y * v.y + w.z * v.z + w.w * v.w;
    }

    #pragma unroll
    for (int off = 32; off > 0; off >>= 1)
        acc += __shfl_xor(acc, off, 64);

    if (lane == 0) {
        float e = acc + b[row];
        int i = row / 3;
        int r = row - 3 * i;
        if (r == 0)      shift[i] = e;
        else if (r == 1) scale[i] = e;
        else             gate[i]  = e;
    }
}

// LN: TWO rows per wave, software-pipelined (row-1 loads issued before the
// row-0 shuffle reduce to hide the 6-stage DS-chain latency). scale/shift
// staged in LDS once per block (24KB, amortized over 8 rows). All register
// arrays fully unrolled / compile-time indexed (round-2 scratch lesson).
__global__ __launch_bounds__(256, 4) void ln_affine_kernel(
    const float* __restrict__ x, const float* __restrict__ shift,
    const float* __restrict__ scale, float* __restrict__ out)
{
    __shared__ float s_sc[DIM];
    __shared__ float s_sh[DIM];
    const int t = threadIdx.x;
    const int wid = t >> 6;
    const int lane = t & 63;

    // stage scale/shift into LDS (from L2/L3 -- every block reads same 24KB)
    {
        const float4* scg = (const float4*)scale;
        const float4* shg = (const float4*)shift;
        float4* ssc = (float4*)s_sc;
        float4* ssh = (float4*)s_sh;
        #pragma unroll
        for (int k = 0; k < 3; ++k) {
            int i = t + k * 256;             // float4 index < 768
            ssc[i] = scg[i];
            ssh[i] = shg[i];
        }
    }
    __syncthreads();
    const float4* lsc = (const float4*)s_sc;
    const float4* lsh = (const float4*)s_sh;

    const int row0 = (blockIdx.x * 4 + wid) * 2;   // grid = SEQ/8 = 1024 blocks
    const int row1 = row0 + 1;
    const float4* xA = (const float4*)(x + (size_t)row0 * DIM);
    const float4* xB = (const float4*)(x + (size_t)row1 * DIM);
    float4* oA = (float4*)(out + (size_t)row0 * DIM);
    float4* oB = (float4*)(out + (size_t)row1 * DIM);

    // ---- load row0 + partial sums ----
    float4 v0[12];
    float sum0 = 0.f, sq0 = 0.f;
    #pragma unroll
    for (int k = 0; k < 12; ++k) {
        v0[k] = xA[lane + 64 * k];
        sum0 += v0[k].x + v0[k].y + v0[k].z + v0[k].w;
        sq0  += v0[k].x * v0[k].x + v0[k].y * v0[k].y + v0[k].z * v0[k].z + v0[k].w * v0[k].w;
    }

    // ---- load row1 (independent; overlaps row0 reduce below) ----
    float4 v1[12];
    float sum1 = 0.f, sq1 = 0.f;
    #pragma unroll
    for (int k = 0; k < 12; ++k) {
        v1[k] = xB[lane + 64 * k];
        sum1 += v1[k].x + v1[k].y + v1[k].z + v1[k].w;
        sq1  += v1[k].x * v1[k].x + v1[k].y * v1[k].y + v1[k].z * v1[k].z + v1[k].w * v1[k].w;
    }

    // ---- reduce row0 ----
    #pragma unroll
    for (int off = 32; off > 0; off >>= 1) {
        sum0 += __shfl_xor(sum0, off, 64);
        sq0  += __shfl_xor(sq0,  off, 64);
    }
    const float mean0 = sum0 * (1.0f / DIM);
    const float rstd0 = rsqrtf(sq0 * (1.0f / DIM) - mean0 * mean0 + 1e-6f);

    // ---- apply row0 (v0 dies here) ----
    #pragma unroll
    for (int k = 0; k < 12; ++k) {
        int i = lane + 64 * k;
        float4 sc = lsc[i];
        float4 sh = lsh[i];
        float4 r;
        r.x = (v0[k].x - mean0) * rstd0 * sc.x + sh.x;
        r.y = (v0[k].y - mean0) * rstd0 * sc.y + sh.y;
        r.z = (v0[k].z - mean0) * rstd0 * sc.z + sh.z;
        r.w = (v0[k].w - mean0) * rstd0 * sc.w + sh.w;
        oA[i] = r;
    }

    // ---- reduce row1 ----
    #pragma unroll
    for (int off = 32; off > 0; off >>= 1) {
        sum1 += __shfl_xor(sum1, off, 64);
        sq1  += __shfl_xor(sq1,  off, 64);
    }
    const float mean1 = sum1 * (1.0f / DIM);
    const float rstd1 = rsqrtf(sq1 * (1.0f / DIM) - mean1 * mean1 + 1e-6f);

    // ---- apply row1 ----
    #pragma unroll
    for (int k = 0; k < 12; ++k) {
        int i = lane + 64 * k;
        float4 sc = lsc[i];
        float4 sh = lsh[i];
        float4 r;
        r.x = (v1[k].x - mean1) * rstd1 * sc.x + sh.x;
        r.y = (v1[k].y - mean1) * rstd1 * sc.y + sh.y;
        r.z = (v1[k].z - mean1) * rstd1 * sc.z + sh.z;
        r.w = (v1[k].w - mean1) * rstd1 * sc.w + sh.w;
        oB[i] = r;
    }
}

extern "C" void kernel_launch(void* const* d_in, const int* in_sizes, int n_in,
                              void* d_out, int out_size, void* d_ws, size_t ws_size,
                              hipStream_t stream) {
    const float* x   = (const float*)d_in[0];  // [1, 8192, 3072]
    const float* emb = (const float*)d_in[1];  // [1, 3072]
    const float* W   = (const float*)d_in[2];  // [9216, 3072]
    const float* b   = (const float*)d_in[3];  // [9216]
    float* out   = (float*)d_out;                      // [1,8192,3072] flat
    float* gate  = out + (size_t)SEQ * DIM;            // [1,3072] appended
    float* shift = (float*)d_ws;                       // [3072]
    float* scale = shift + DIM;                        // [3072]

    gemv3_kernel<<<NROWS / 4, 256, 0, stream>>>(emb, W, b, shift, scale, gate);
    ln_affine_kernel<<<SEQ / 8, 256, 0, stream>>>(x, shift, scale, out);
}